// Round 1
// baseline (1099.648 us; speedup 1.0000x reference)
//
#include <hip/hip_runtime.h>

#define EPSF 1e-5f

constexpr int Sn = 5, Bn = 8, Hin = 512, Win = 512, Cn = 64;
constexpr int HO = 257, WO = 257;
constexpr int HW = HO * WO;           // 66049
constexpr int NPIX = Bn * HW;         // 528392 pixels per scale
constexpr int TOTPIX = Sn * NPIX;     // 2641960

// Kernel 1: DWT. One thread per (s, b, i, j). Computes L and Hc.
// L[i,j] = l0*(l0*x[2i-1,2j-1] + l1*x[2i-1,2j]) + l1*(l0*x[2i,2j-1] + l1*x[2i,2j])
// with zero padding outside [0,512).
__global__ __launch_bounds__(256) void dwt_kernel(
    const float* __restrict__ x,
    const float* __restrict__ lp,
    const float* __restrict__ hp,
    float* __restrict__ Lout,
    float* __restrict__ Hout) {
    int gid = blockIdx.x * blockDim.x + threadIdx.x;
    if (gid >= TOTPIX) return;
    int s  = gid / NPIX;
    int r  = gid - s * NPIX;
    int b  = r / HW;
    int hw = r - b * HW;
    int i  = hw / WO;
    int j  = hw - i * WO;

    float l0 = lp[2*s], l1 = lp[2*s+1];
    float h0 = hp[2*s], h1 = hp[2*s+1];

    int r0 = 2*i - 1, r1 = 2*i;
    int c0 = 2*j - 1, c1 = 2*j;
    const float* xb = x + (size_t)b * (Hin * Win);
    // r0 >= -1, r0 <= 511 always; r1 <= 512 (OOB at i=256). Same for cols.
    float x00 = (r0 >= 0   && c0 >= 0 ) ? xb[r0*Win + c0] : 0.f;
    float x01 = (r0 >= 0   && c1 < Win) ? xb[r0*Win + c1] : 0.f;
    float x10 = (r1 < Hin  && c0 >= 0 ) ? xb[r1*Win + c0] : 0.f;
    float x11 = (r1 < Hin  && c1 < Win) ? xb[r1*Win + c1] : 0.f;

    float Lv = l0*(l0*x00 + l1*x01) + l1*(l0*x10 + l1*x11);
    float Hv = h0*(h0*x00 + h1*x01) + h1*(h0*x10 + h1*x11);

    // Layout [S,B,1,HO,WO] flat == gid
    Lout[gid] = Lv;
    Hout[gid] = Hv;
}

// Kernel 2: per-pixel scalar->64 channel MLP (conv1x1 + BN + ReLU, twice).
// grid = (pixel blocks, scale). One pixel per thread.
__global__ __launch_bounds__(256) void proc_kernel(
    const float* __restrict__ Lout,
    const float* __restrict__ w1, const float* __restrict__ w2,
    const float* __restrict__ g1, const float* __restrict__ b1,
    const float* __restrict__ m1, const float* __restrict__ v1,
    const float* __restrict__ g2, const float* __restrict__ b2,
    const float* __restrict__ m2, const float* __restrict__ v2,
    float* __restrict__ Pout) {
    __shared__ float sw[Cn * Cn];            // w2f[o][c] = s2[o]*w2[s][o][c]
    __shared__ float sa1[Cn], st1[Cn], st2[Cn], ss2[Cn];

    int tid = threadIdx.x;
    int s   = blockIdx.y;

    if (tid < Cn) {
        int idx = s * Cn + tid;
        float sc1 = g1[idx] / sqrtf(v1[idx] + EPSF);
        sa1[tid] = sc1 * w1[idx];            // w1 shape (S,C,1)
        st1[tid] = b1[idx] - m1[idx] * sc1;
        float sc2 = g2[idx] / sqrtf(v2[idx] + EPSF);
        ss2[tid] = sc2;
        st2[tid] = b2[idx] - m2[idx] * sc2;
    }
    __syncthreads();
    {
        const float* w2s = w2 + (size_t)s * Cn * Cn;
        for (int t = tid; t < Cn * Cn; t += 256)
            sw[t] = w2s[t] * ss2[t >> 6];
    }
    __syncthreads();

    int p = blockIdx.x * 256 + tid;
    float v = 0.f;
    if (p < NPIX) v = Lout[s * NPIX + p];

    // First layer: y1[c] = relu(a1[c]*v + t1[c]) — 64 registers.
    float y1[Cn];
    #pragma unroll
    for (int c = 0; c < Cn; c++)
        y1[c] = fmaxf(fmaf(sa1[c], v, st1[c]), 0.f);

    if (p >= NPIX) return;

    int b  = p / HW;
    int hw = p - b * HW;
    float* Pp = Pout + ((size_t)(s * Bn + b) * Cn) * HW + hw;

    // Second layer: 64x64 matvec from LDS (broadcast reads), 4 acc chains for ILP.
    for (int o = 0; o < Cn; o++) {
        const float4* w4 = (const float4*)(sw + o * Cn);
        float a0 = st2[o], a1c = 0.f, a2c = 0.f, a3c = 0.f;
        #pragma unroll
        for (int q = 0; q < Cn / 4; q++) {
            float4 w = w4[q];
            a0  = fmaf(w.x, y1[4*q+0], a0);
            a1c = fmaf(w.y, y1[4*q+1], a1c);
            a2c = fmaf(w.z, y1[4*q+2], a2c);
            a3c = fmaf(w.w, y1[4*q+3], a3c);
        }
        float acc = (a0 + a1c) + (a2c + a3c);
        Pp[(size_t)o * HW] = fmaxf(acc, 0.f);   // coalesced: lanes->consecutive hw
    }
}

extern "C" void kernel_launch(void* const* d_in, const int* in_sizes, int n_in,
                              void* d_out, int out_size, void* d_ws, size_t ws_size,
                              hipStream_t stream) {
    const float* x  = (const float*)d_in[0];
    const float* lp = (const float*)d_in[1];
    const float* hp = (const float*)d_in[2];
    const float* w1 = (const float*)d_in[3];
    const float* w2 = (const float*)d_in[4];
    const float* g1 = (const float*)d_in[5];
    const float* b1 = (const float*)d_in[6];
    const float* m1 = (const float*)d_in[7];
    const float* v1 = (const float*)d_in[8];
    const float* g2 = (const float*)d_in[9];
    const float* b2 = (const float*)d_in[10];
    const float* m2 = (const float*)d_in[11];
    const float* v2 = (const float*)d_in[12];

    float* out  = (float*)d_out;
    float* Lout = out;                  // [5,8,1,257,257]
    float* Hout = out + TOTPIX;         // [5,8,1,257,257]
    float* Pout = out + 2 * TOTPIX;     // [5,8,64,257,257]

    dwt_kernel<<<(TOTPIX + 255) / 256, 256, 0, stream>>>(x, lp, hp, Lout, Hout);

    dim3 grid((NPIX + 255) / 256, Sn);
    proc_kernel<<<grid, 256, 0, stream>>>(Lout, w1, w2, g1, b1, m1, v1,
                                          g2, b2, m2, v2, Pout);
}

// Round 2
// 853.874 us; speedup vs baseline: 1.2878x; 1.2878x over previous
//
#include <hip/hip_runtime.h>
#include <math.h>

#define EPSF 1e-5f

constexpr int Sn = 5, Bn = 8, Hin = 512, Win = 512, Cn = 64;
constexpr int HO = 257, WO = 257;
constexpr int HW = HO * WO;           // 66049
constexpr int NPIX = Bn * HW;         // 528392 pixels per scale
constexpr int TOTPIX = Sn * NPIX;     // 2641960

// Workspace layout per scale (floats):
//   [0,64)          : sorted breakpoints tS[64]
//   [64, 64+64*66*2): alpha/beta as float2 ab[o][r], row stride 66 (r in [0,65))
constexpr int WSF = 64 + Cn * 66 * 2;  // 8512 floats per scale

// ---------------------------------------------------------------------------
// Precompute: for each scale, build the piecewise-linear table of the
// scalar->64ch MLP:  P[o](v) = relu(alpha[o][r]*v + beta[o][r]) where r is the
// region of v among the 64 sorted ReLU breakpoints t_c = -t1[c]/a1[c].
// One block per scale, 64 threads (thread == channel == output row).
// ---------------------------------------------------------------------------
__global__ __launch_bounds__(64) void precompute_kernel(
    const float* __restrict__ w1, const float* __restrict__ w2,
    const float* __restrict__ g1, const float* __restrict__ b1,
    const float* __restrict__ m1, const float* __restrict__ v1,
    const float* __restrict__ g2, const float* __restrict__ b2,
    const float* __restrict__ m2, const float* __restrict__ v2,
    float* __restrict__ ws) {
    int s = blockIdx.x;
    int c = threadIdx.x;
    __shared__ float sa1[Cn], st1[Cn], stc[Cn], stS[Cn];
    __shared__ int   scS[Cn];

    int idx = s * Cn + c;
    float sc1 = g1[idx] / sqrtf(v1[idx] + EPSF);
    float a1  = sc1 * w1[idx];                 // w1 shape (S,C,1)
    float t1  = b1[idx] - m1[idx] * sc1;
    sa1[c] = a1;
    st1[c] = t1;
    float tc = (a1 != 0.f) ? (-t1 / a1) : INFINITY;
    stc[c] = tc;
    __syncthreads();

    // rank sort (64^2 compares), ties broken by index
    int rk = 0;
    for (int c2 = 0; c2 < Cn; c2++) {
        float t = stc[c2];
        rk += (t < tc) || (t == tc && c2 < c);
    }
    stS[rk] = tc;
    scS[rk] = c;
    __syncthreads();

    float* wss = ws + (size_t)s * WSF;
    wss[c] = stS[c];

    int o = c;
    float sc2 = g2[idx] / sqrtf(v2[idx] + EPSF);
    float t2o = b2[idx] - m2[idx] * sc2;
    const float* w2row = w2 + ((size_t)s * Cn + o) * Cn;

    // base region r=0 (v below all breakpoints): active channels are a1<0
    // (a1*v -> +inf), plus a1==0 with t1>0 (constant).
    float alpha = 0.f, beta = t2o;
    for (int cc = 0; cc < Cn; cc++) {
        float a = sa1[cc];
        bool act = (a < 0.f) || (a == 0.f && st1[cc] > 0.f);
        if (act) {
            float wf = sc2 * w2row[cc];
            alpha = fmaf(wf, a, alpha);
            beta  = fmaf(wf, st1[cc], beta);
        }
    }
    float2* abrow = (float2*)(wss + Cn);
    abrow[o * 66 + 0] = make_float2(alpha, beta);

    // sweep regions: crossing sorted breakpoint k toggles channel scS[k]
    for (int r = 1; r <= Cn; r++) {
        int cc = scS[r - 1];
        float a = sa1[cc];
        if (a != 0.f) {
            float wf = sc2 * w2row[cc];
            float sgn = (a > 0.f) ? 1.f : -1.f;   // on when crossing up if a>0
            alpha = fmaf(sgn * wf, a, alpha);
            beta  = fmaf(sgn * wf, st1[cc], beta);
        }
        abrow[o * 66 + r] = make_float2(alpha, beta);
    }
}

// ---------------------------------------------------------------------------
// Fused DWT + PWL-MLP. grid = (pixel tiles, scale). 256 thr, PPT pixels each.
// Per pixel: 4 x loads -> L,Hc (stored), binary-search region of L, then
// 64 x (ds_read_b64 + fma + max + coalesced store).
// ---------------------------------------------------------------------------
constexpr int PPT = 4;

__global__ __launch_bounds__(256) void fused_kernel(
    const float* __restrict__ x,
    const float* __restrict__ lp, const float* __restrict__ hp,
    const float* __restrict__ ws,
    float* __restrict__ Lout, float* __restrict__ Hout,
    float* __restrict__ Pout) {
    __shared__ float  stS[Cn];
    __shared__ float2 sab[Cn * 66];

    int tid = threadIdx.x;
    int s   = blockIdx.y;
    const float* wss = ws + (size_t)s * WSF;
    if (tid < Cn) stS[tid] = wss[tid];
    const float2* abg = (const float2*)(wss + Cn);
    for (int t = tid; t < Cn * 66; t += 256) sab[t] = abg[t];
    __syncthreads();

    float l0 = lp[2 * s], l1 = lp[2 * s + 1];
    float h0 = hp[2 * s], h1 = hp[2 * s + 1];

    for (int k = 0; k < PPT; k++) {
        int p = (blockIdx.x * PPT + k) * 256 + tid;
        if (p >= NPIX) return;
        int b  = p / HW;
        int hw = p - b * HW;
        int i  = hw / WO;
        int j  = hw - i * WO;

        int r0 = 2 * i - 1, r1 = 2 * i;
        int c0 = 2 * j - 1, c1 = 2 * j;
        const float* xb = x + (size_t)b * (Hin * Win);
        float x00 = (r0 >= 0  && c0 >= 0 ) ? xb[r0 * Win + c0] : 0.f;
        float x01 = (r0 >= 0  && c1 < Win) ? xb[r0 * Win + c1] : 0.f;
        float x10 = (r1 < Hin && c0 >= 0 ) ? xb[r1 * Win + c0] : 0.f;
        float x11 = (r1 < Hin && c1 < Win) ? xb[r1 * Win + c1] : 0.f;

        float Lv = l0 * (l0 * x00 + l1 * x01) + l1 * (l0 * x10 + l1 * x11);
        float Hv = h0 * (h0 * x00 + h1 * x01) + h1 * (h0 * x10 + h1 * x11);

        size_t gid = (size_t)s * NPIX + p;
        Lout[gid] = Lv;
        Hout[gid] = Hv;

        // region = count of breakpoints < Lv  (binary search, 7 steps)
        int lo = 0, hi = Cn;
        while (lo < hi) {
            int mid = (lo + hi) >> 1;
            if (stS[mid] < Lv) lo = mid + 1; else hi = mid;
        }

        float* Pp = Pout + ((size_t)(s * Bn + b) * Cn) * HW + hw;
        #pragma unroll 16
        for (int o = 0; o < Cn; o++) {
            float2 ab = sab[o * 66 + lo];
            Pp[(size_t)o * HW] = fmaxf(fmaf(ab.x, Lv, ab.y), 0.f);
        }
    }
}

extern "C" void kernel_launch(void* const* d_in, const int* in_sizes, int n_in,
                              void* d_out, int out_size, void* d_ws, size_t ws_size,
                              hipStream_t stream) {
    const float* x  = (const float*)d_in[0];
    const float* lp = (const float*)d_in[1];
    const float* hp = (const float*)d_in[2];
    const float* w1 = (const float*)d_in[3];
    const float* w2 = (const float*)d_in[4];
    const float* g1 = (const float*)d_in[5];
    const float* b1 = (const float*)d_in[6];
    const float* m1 = (const float*)d_in[7];
    const float* v1 = (const float*)d_in[8];
    const float* g2 = (const float*)d_in[9];
    const float* b2 = (const float*)d_in[10];
    const float* m2 = (const float*)d_in[11];
    const float* v2 = (const float*)d_in[12];

    float* out  = (float*)d_out;
    float* Lout = out;                  // [5,8,1,257,257]
    float* Hout = out + TOTPIX;         // [5,8,1,257,257]
    float* Pout = out + 2 * TOTPIX;     // [5,8,64,257,257]
    float* ws   = (float*)d_ws;         // 5 * WSF floats = 170 KB

    precompute_kernel<<<Sn, Cn, 0, stream>>>(w1, w2, g1, b1, m1, v1,
                                             g2, b2, m2, v2, ws);

    int blocksPerScale = (NPIX + 256 * PPT - 1) / (256 * PPT);  // 517
    dim3 grid(blocksPerScale, Sn);
    fused_kernel<<<grid, 256, 0, stream>>>(x, lp, hp, ws, Lout, Hout, Pout);
}